// Round 10
// baseline (186.829 us; speedup 1.0000x reference)
//
#include <hip/hip_runtime.h>
#include <hip/hip_bf16.h>

#define N_NODES 100000
#define N_EDGES 3200000
#define DIM 128
#define HID 32

#define BSH 6                                   // bucket = dst >> 6
#define BNODES (1 << BSH)                       // 64 nodes per bucket
#define NBUK ((N_NODES + BNODES - 1) >> BSH)    // 1563
#define NBP 2048                                // padded (pow2) bucket count
#define FCHUNK 8192                             // edges per partition block (57KB LDS, 2 blk/CU)
#define NFILL ((N_EDGES + FCHUNK - 1) / FCHUNK) // 391
#define SLAB 3072                               // per-bucket sort cap (mean 2048, +22 sigma)

typedef short v8s __attribute__((ext_vector_type(8)));
typedef float v4f __attribute__((ext_vector_type(4)));

__device__ __forceinline__ float bf_lo(unsigned int u) { return __uint_as_float(u << 16); }
__device__ __forceinline__ float bf_hi(unsigned int u) { return __uint_as_float(u & 0xFFFF0000u); }
__device__ __forceinline__ unsigned int pk2(float a, float b) {
    __hip_bfloat162 p = __float22bfloat162_rn(make_float2(a, b));
    union { __hip_bfloat162 h; unsigned int u; } cv; cv.h = p; return cv.u;
}

// Workspace: bcnt[NBP] boff[NBP] gcur[NBP] ebuf[E] rowptr[NBUK*64+4] dinv[N]
//            y1a[N*8] y1b[N*8] pA[N] y2[N]

__global__ void k_zeroB(int* __restrict__ bcnt) {
    int i = blockIdx.x * blockDim.x + threadIdx.x;
    if (i < NBP) bcnt[i] = 0;
}

// global bucket histogram via per-block LDS histogram (int4 edge reads)
__launch_bounds__(256)
__global__ void k_bhist(const int* __restrict__ dst, int* __restrict__ bcnt) {
    __shared__ int h[NBP];
    for (int i = threadIdx.x; i < NBP; i += 256) h[i] = 0;
    __syncthreads();
    const int4* d4 = (const int4*)dst;
    int stride = gridDim.x * blockDim.x;
    for (int e = blockIdx.x * blockDim.x + threadIdx.x; e < N_EDGES / 4; e += stride) {
        int4 v = d4[e];
        atomicAdd(&h[v.x >> BSH], 1);
        atomicAdd(&h[v.y >> BSH], 1);
        atomicAdd(&h[v.z >> BSH], 1);
        atomicAdd(&h[v.w >> BSH], 1);
    }
    __syncthreads();
    for (int i = threadIdx.x; i < NBP; i += 256)
        if (h[i]) atomicAdd(&bcnt[i], h[i]);
}

// single block: exclusive scan of bcnt[NBP] -> boff, working copy -> gcur
__global__ void k_bscan(const int* __restrict__ bcnt, int* __restrict__ boff,
                        int* __restrict__ gcur) {
    __shared__ int s[256];
    int t = threadIdx.x;
    int c[8]; int sum = 0;
    #pragma unroll
    for (int k = 0; k < 8; ++k) { c[k] = bcnt[t * 8 + k]; sum += c[k]; }
    s[t] = sum; __syncthreads();
    for (int d = 1; d < 256; d <<= 1) {
        int add = (t >= d) ? s[t - d] : 0;
        __syncthreads();
        s[t] += add;
        __syncthreads();
    }
    int excl = s[t] - sum;
    #pragma unroll
    for (int k = 0; k < 8; ++k) {
        boff[t * 8 + k] = excl;
        gcur[t * 8 + k] = excl;
        excl += c[k];
    }
}

// Partition edges into bucket-ordered ebuf with LDS staging + coalesced flush.
// packed edge = (dst & 63) << 20 | src   (src < 2^17)
// int4 loads: 8 latency-serialized iterations per phase instead of 32.
// Flush bucket lookup by binary search over offA (no sbuk -> 57KB LDS, 2 blk/CU).
__launch_bounds__(256)
__global__ void k_bfill(const int* __restrict__ src, const int* __restrict__ dst,
                        int* __restrict__ gcur, unsigned int* __restrict__ ebuf) {
    __shared__ int cntA[NBP];               // pass-1 counts, then reused as pass-2 cursors
    __shared__ int offA[NBP];               // exclusive offsets within chunk
    __shared__ int baseG[NBP];              // reserved global base per bucket
    __shared__ int ssum[256];
    __shared__ unsigned int stage[FCHUNK];  // 32 KB
    int t = threadIdx.x;
    int e0 = blockIdx.x * FCHUNK;
    int eN = min(e0 + FCHUNK, N_EDGES) - e0;       // always a multiple of 4
    const int4* d4 = (const int4*)(dst + e0);
    const int4* s4 = (const int4*)(src + e0);
    int n4 = eN >> 2;
    for (int i = t; i < NBP; i += 256) cntA[i] = 0;
    __syncthreads();
    // pass 1: count buckets in this chunk (vectorized)
    for (int i = t; i < n4; i += 256) {
        int4 d = d4[i];
        atomicAdd(&cntA[d.x >> BSH], 1);
        atomicAdd(&cntA[d.y >> BSH], 1);
        atomicAdd(&cntA[d.z >> BSH], 1);
        atomicAdd(&cntA[d.w >> BSH], 1);
    }
    __syncthreads();
    // LDS exclusive scan cntA -> offA (8 elems/thread)
    {
        int c[8]; int sum = 0;
        #pragma unroll
        for (int k = 0; k < 8; ++k) { c[k] = cntA[t * 8 + k]; sum += c[k]; }
        ssum[t] = sum; __syncthreads();
        for (int d = 1; d < 256; d <<= 1) {
            int add = (t >= d) ? ssum[t - d] : 0;
            __syncthreads();
            ssum[t] += add;
            __syncthreads();
        }
        int excl = ssum[t] - sum;
        #pragma unroll
        for (int k = 0; k < 8; ++k) { offA[t * 8 + k] = excl; excl += c[k]; }
    }
    __syncthreads();
    // reserve global space per bucket (counts are final)
    for (int b = t; b < NBP; b += 256)
        if (cntA[b] > 0) baseG[b] = atomicAdd(&gcur[b], cntA[b]);
    __syncthreads();
    // reuse cntA as pass-2 cursors
    for (int i = t; i < NBP; i += 256) cntA[i] = 0;
    __syncthreads();
    // pass 2: re-read edges (vectorized), place packed into LDS stage
    for (int i = t; i < n4; i += 256) {
        int4 d = d4[i];
        int4 s = s4[i];
        int b0 = d.x >> BSH, b1 = d.y >> BSH, b2 = d.z >> BSH, b3 = d.w >> BSH;
        int p0 = offA[b0] + atomicAdd(&cntA[b0], 1);
        int p1 = offA[b1] + atomicAdd(&cntA[b1], 1);
        int p2 = offA[b2] + atomicAdd(&cntA[b2], 1);
        int p3 = offA[b3] + atomicAdd(&cntA[b3], 1);
        stage[p0] = ((unsigned int)(d.x & (BNODES - 1)) << 20) | (unsigned int)s.x;
        stage[p1] = ((unsigned int)(d.y & (BNODES - 1)) << 20) | (unsigned int)s.y;
        stage[p2] = ((unsigned int)(d.z & (BNODES - 1)) << 20) | (unsigned int)s.z;
        stage[p3] = ((unsigned int)(d.w & (BNODES - 1)) << 20) | (unsigned int)s.w;
    }
    __syncthreads();
    // coalesced flush: stage index i -> bucket via binary search (largest b: offA[b] <= i)
    for (int i = t; i < eN; i += 256) {
        int lo = 0, hi = NBP - 1;
        while (lo < hi) {
            int mid = (lo + hi + 1) >> 1;
            if (offA[mid] <= i) lo = mid; else hi = mid - 1;
        }
        ebuf[baseG[lo] + (i - offA[lo])] = stage[i];
    }
}

// Per-bucket LDS counting sort by dlocal -> ebuf globally dst-sorted (CSR order).
// Also emits rowptr[v] (global row starts) and dinv[v] = rsqrt(deg+1).
__launch_bounds__(256)
__global__ void k_sort(unsigned int* __restrict__ ebuf, const int* __restrict__ boff,
                       const int* __restrict__ bcnt, int* __restrict__ rowptr,
                       float* __restrict__ dinv) {
    __shared__ unsigned int slab[SLAB];    // 12 KB
    __shared__ unsigned int slab2[SLAB];   // 12 KB
    __shared__ int hist[BNODES];
    __shared__ int scanx[BNODES];
    __shared__ int cur[BNODES];
    int t = threadIdx.x;
    int b = blockIdx.x;
    int s0 = boff[b];
    int n = min(bcnt[b], SLAB);
    if (t < BNODES) hist[t] = 0;
    __syncthreads();
    for (int i = t; i < n; i += 256) {
        unsigned int w = ebuf[s0 + i];
        slab[i] = w;
        atomicAdd(&hist[w >> 20], 1);
    }
    __syncthreads();
    if (t == 0) {
        int r = 0;
        for (int l = 0; l < BNODES; ++l) { scanx[l] = r; r += hist[l]; }
    }
    __syncthreads();
    if (t < BNODES) {
        cur[t] = scanx[t];
        int v = b * BNODES + t;
        rowptr[v] = s0 + scanx[t];
        if (v < N_NODES) dinv[v] = rsqrtf((float)(hist[t] + 1));
    }
    if (b == 0 && t == 0) rowptr[NBUK * BNODES] = N_EDGES;
    __syncthreads();
    for (int i = t; i < n; i += 256) {
        unsigned int w = slab[i];
        int pos = atomicAdd(&cur[w >> 20], 1);
        slab2[pos] = w;
    }
    __syncthreads();
    for (int i = t; i < n; i += 256) ebuf[s0 + i] = slab2[i];
}

// y1 = bf16-packed rows of dinv[v] * (x @ W1), via MFMA 16x16x32 bf16.
// Column-split output: y1a = cols 0..15 (32B rows), y1b = cols 16..31.
__launch_bounds__(256)
__global__ void k_gemm1(const float* __restrict__ x, const float* __restrict__ W1,
                        const float* __restrict__ dinv, unsigned int* __restrict__ y1a,
                        unsigned int* __restrict__ y1b) {
    int wv = (blockIdx.x * 256 + threadIdx.x) >> 6;
    int nwaves = (gridDim.x * 256) >> 6;
    int lane = threadIdx.x & 63;
    int m = lane & 15;
    int kb = lane >> 4;                   // 0..3
    v8s Bf[2][4];                         // B fragments: [ntile][kstep]
    #pragma unroll
    for (int tt = 0; tt < 2; ++tt)
        #pragma unroll
        for (int s = 0; s < 4; ++s) {
            union { unsigned int u[4]; v8s v; } ub;
            #pragma unroll
            for (int jj = 0; jj < 4; ++jj) {
                int k = s * 32 + kb * 8 + jj * 2;
                ub.u[jj] = pk2(W1[k * HID + tt * 16 + m], W1[(k + 1) * HID + tt * 16 + m]);
            }
            Bf[tt][s] = ub.v;
        }
    for (int tile = wv; tile < N_NODES / 16; tile += nwaves) {   // 6250 exact, no tail
        int base = tile * 16;
        const float* xr = x + (size_t)(base + m) * DIM;
        v4f acc0 = {0.f, 0.f, 0.f, 0.f}, acc1 = {0.f, 0.f, 0.f, 0.f};
        #pragma unroll
        for (int s = 0; s < 4; ++s) {
            float4 xa = *(const float4*)(xr + s * 32 + kb * 8);
            float4 xb = *(const float4*)(xr + s * 32 + kb * 8 + 4);
            union { unsigned int u[4]; v8s v; } ua;
            ua.u[0] = pk2(xa.x, xa.y); ua.u[1] = pk2(xa.z, xa.w);
            ua.u[2] = pk2(xb.x, xb.y); ua.u[3] = pk2(xb.z, xb.w);
            acc0 = __builtin_amdgcn_mfma_f32_16x16x32_bf16(ua.v, Bf[0][s], acc0, 0, 0, 0);
            acc1 = __builtin_amdgcn_mfma_f32_16x16x32_bf16(ua.v, Bf[1][s], acc1, 0, 0, 0);
        }
        float4 dv = *(const float4*)(dinv + base + kb * 4);     // rows kb*4..kb*4+3
        float d[4] = {dv.x, dv.y, dv.z, dv.w};
        #pragma unroll
        for (int r = 0; r < 4; ++r) {
            float v0 = acc0[r] * d[r];
            float v1 = acc1[r] * d[r];
            float p0 = __shfl_xor(v0, 1, 64);                   // partner col
            float p1 = __shfl_xor(v1, 1, 64);
            if ((m & 1) == 0) {
                int node = base + kb * 4 + r;
                y1a[node * 8 + (m >> 1)] = pk2(v0, p0);         // cols m, m+1
                y1b[node * 8 + (m >> 1)] = pk2(v1, p1);         // cols 16+m, 17+m
            }
        }
    }
}

// Layer-1 gather over an L2-RESIDENT half-table (3.2MB): 32 lanes per node =
// 4 edge-subsets x 8 uint-lanes; batch of 32 edges per broadcast ebuf load,
// 8 independent 32B row loads in flight. HALF=0: cols 0..15 -> out_h, pA.
// HALF=1: cols 16..31 -> out_h, y2 = dinv*(pA + pB).
template <int HALF>
__launch_bounds__(256)
__global__ void k_gather1(const int* __restrict__ rowptr, const unsigned int* __restrict__ ebuf,
                          const unsigned int* __restrict__ yh, const float* __restrict__ dinv,
                          const float* __restrict__ b1, const float* __restrict__ W2,
                          float* __restrict__ out_h, float* __restrict__ pA,
                          float* __restrict__ y2) {
    int t = threadIdx.x;
    int node = blockIdx.x * 8 + (t >> 5);
    if (node >= N_NODES) return;
    int lane = t & 31;
    int sub = lane >> 3;                  // edge subset 0..3
    int c = lane & 7;                     // uint index in 32B row (cols 2c, 2c+1)
    int start = rowptr[node], end = rowptr[node + 1];
    float l0 = 0.f, l1 = 0.f, l2 = 0.f, l3 = 0.f;
    float h0 = 0.f, h1 = 0.f, h2 = 0.f, h3 = 0.f;
    int j = start;
    for (; j + 32 <= end; j += 32) {
        unsigned int w = ebuf[j + lane];             // 32 consecutive words
        unsigned int e0 = (unsigned int)__shfl((int)w, 0  + sub, 32) & 0xFFFFF;
        unsigned int e1 = (unsigned int)__shfl((int)w, 4  + sub, 32) & 0xFFFFF;
        unsigned int e2 = (unsigned int)__shfl((int)w, 8  + sub, 32) & 0xFFFFF;
        unsigned int e3 = (unsigned int)__shfl((int)w, 12 + sub, 32) & 0xFFFFF;
        unsigned int e4 = (unsigned int)__shfl((int)w, 16 + sub, 32) & 0xFFFFF;
        unsigned int e5 = (unsigned int)__shfl((int)w, 20 + sub, 32) & 0xFFFFF;
        unsigned int e6 = (unsigned int)__shfl((int)w, 24 + sub, 32) & 0xFFFFF;
        unsigned int e7 = (unsigned int)__shfl((int)w, 28 + sub, 32) & 0xFFFFF;
        unsigned int v0 = yh[(size_t)e0 * 8 + c];    // 8 independent 32B row loads
        unsigned int v1 = yh[(size_t)e1 * 8 + c];
        unsigned int v2 = yh[(size_t)e2 * 8 + c];
        unsigned int v3 = yh[(size_t)e3 * 8 + c];
        unsigned int v4 = yh[(size_t)e4 * 8 + c];
        unsigned int v5 = yh[(size_t)e5 * 8 + c];
        unsigned int v6 = yh[(size_t)e6 * 8 + c];
        unsigned int v7 = yh[(size_t)e7 * 8 + c];
        l0 += bf_lo(v0); h0 += bf_hi(v0);
        l1 += bf_lo(v1); h1 += bf_hi(v1);
        l2 += bf_lo(v2); h2 += bf_hi(v2);
        l3 += bf_lo(v3); h3 += bf_hi(v3);
        l0 += bf_lo(v4); h0 += bf_hi(v4);
        l1 += bf_lo(v5); h1 += bf_hi(v5);
        l2 += bf_lo(v6); h2 += bf_hi(v6);
        l3 += bf_lo(v7); h3 += bf_hi(v7);
    }
    int navail = end - j;                 // 0..31 tail edges
    if (navail > 0) {
        unsigned int w = ebuf[min(j + lane, end - 1)];
        #pragma unroll
        for (int k = 0; k < 8; ++k) {
            int idx = k * 4 + sub;
            unsigned int u = (unsigned int)__shfl((int)w, idx, 32) & 0xFFFFF;
            if (idx < navail) {
                unsigned int v = yh[(size_t)u * 8 + c];
                l0 += bf_lo(v); h0 += bf_hi(v);
            }
        }
    }
    float alo = (l0 + l1) + (l2 + l3);
    float ahi = (h0 + h1) + (h2 + h3);
    alo += __shfl_xor(alo, 8, 32);        // combine edge subsets
    ahi += __shfl_xor(ahi, 8, 32);
    alo += __shfl_xor(alo, 16, 32);
    ahi += __shfl_xor(ahi, 16, 32);
    unsigned int sv = yh[(size_t)node * 8 + c];      // self loop
    alo += bf_lo(sv); ahi += bf_hi(sv);
    float di = dinv[node];
    int col = HALF * 16 + 2 * c;
    float hlo = fmaxf(fmaf(di, alo, b1[col]), 0.f);
    float hhi = fmaxf(fmaf(di, ahi, b1[col + 1]), 0.f);
    float p = hlo * W2[col] + hhi * W2[col + 1];
    p += __shfl_xor(p, 1, 32);
    p += __shfl_xor(p, 2, 32);
    p += __shfl_xor(p, 4, 32);            // sum over 8 col-lanes (subsets identical)
    if (sub == 0) {
        *(float2*)&out_h[(size_t)node * HID + col] = make_float2(hlo, hhi);
        if (c == 0) {
            if (HALF == 0) pA[node] = p;
            else           y2[node] = di * (pA[node] + p);
        }
    }
}

// Layer-2 gather, CSR-style: 32 lanes stride the node's edge run (coalesced ebuf reads).
__launch_bounds__(256)
__global__ void k_gather2(const int* __restrict__ rowptr, const unsigned int* __restrict__ ebuf,
                          const float* __restrict__ y2, const float* __restrict__ dinv,
                          const float* __restrict__ b2, float* __restrict__ scores) {
    int t = threadIdx.x;
    int node = blockIdx.x * 8 + (t >> 5);
    int lane = t & 31;
    if (node >= N_NODES) return;
    int start = rowptr[node], end = rowptr[node + 1];
    float acc = 0.f;
    for (int j = start + lane; j < end; j += 32)
        acc += y2[ebuf[j] & 0xFFFFF];
    #pragma unroll
    for (int off = 16; off > 0; off >>= 1) acc += __shfl_xor(acc, off);
    if (lane == 0) scores[node] = dinv[node] * (acc + y2[node]) + b2[0];
}

extern "C" void kernel_launch(void* const* d_in, const int* in_sizes, int n_in,
                              void* d_out, int out_size, void* d_ws, size_t ws_size,
                              hipStream_t stream) {
    const float* x  = (const float*)d_in[0];
    const int* ei   = (const int*)d_in[1];
    const float* W1 = (const float*)d_in[2];
    const float* b1 = (const float*)d_in[3];
    const float* W2 = (const float*)d_in[4];
    const float* b2 = (const float*)d_in[5];

    const int* src = ei;             // edge_index[0]
    const int* dst = ei + N_EDGES;   // edge_index[1]

    int* bcnt = (int*)d_ws;                             // NBP
    int* boff = bcnt + NBP;                             // NBP
    int* gcur = boff + NBP;                             // NBP
    unsigned int* ebuf = (unsigned int*)(gcur + NBP);   // E
    int* rowptr = (int*)(ebuf + N_EDGES);               // NBUK*BNODES + 4
    float* dinv = (float*)(rowptr + NBUK * BNODES + 4); // N
    unsigned int* y1a = (unsigned int*)(dinv + N_NODES);// N*8 (bf16 cols 0..15)
    unsigned int* y1b = y1a + (size_t)N_NODES * 8;      // N*8 (bf16 cols 16..31)
    float* pA   = (float*)(y1b + (size_t)N_NODES * 8);  // N
    float* y2   = pA + N_NODES;                         // N

    float* out_h = (float*)d_out;                       // N*HID
    float* out_s = out_h + (size_t)N_NODES * HID;       // N

    k_zeroB <<<NBP / 256, 256, 0, stream>>>(bcnt);
    k_bhist <<<512, 256, 0, stream>>>(dst, bcnt);
    k_bscan <<<1, 256, 0, stream>>>(bcnt, boff, gcur);
    k_bfill <<<NFILL, 256, 0, stream>>>(src, dst, gcur, ebuf);
    k_sort  <<<NBUK, 256, 0, stream>>>(ebuf, boff, bcnt, rowptr, dinv);
    k_gemm1 <<<512, 256, 0, stream>>>(x, W1, dinv, y1a, y1b);
    k_gather1<0><<<(N_NODES + 7) / 8, 256, 0, stream>>>(rowptr, ebuf, y1a, dinv, b1, W2, out_h, pA, y2);
    k_gather1<1><<<(N_NODES + 7) / 8, 256, 0, stream>>>(rowptr, ebuf, y1b, dinv, b1, W2, out_h, pA, y2);
    k_gather2<<<(N_NODES + 7) / 8, 256, 0, stream>>>(rowptr, ebuf, y2, dinv, b2, out_s);
}

// Round 11
// 164.172 us; speedup vs baseline: 1.1380x; 1.1380x over previous
//
#include <hip/hip_runtime.h>
#include <hip/hip_bf16.h>

#define N_NODES 100000
#define N_EDGES 3200000
#define DIM 128
#define HID 32

#define BSH 6                                   // bucket = dst >> 6
#define BNODES (1 << BSH)                       // 64 nodes per bucket
#define NBUK ((N_NODES + BNODES - 1) >> BSH)    // 1563
#define NBP 2048                                // padded (pow2) bucket count
#define FCHUNK 8192                             // edges per partition block
#define NFILL ((N_EDGES + FCHUNK - 1) / FCHUNK) // 391
#define SLAB 3072                               // per-bucket sort cap (mean 2048, +22 sigma)

typedef short v8s __attribute__((ext_vector_type(8)));
typedef float v4f __attribute__((ext_vector_type(4)));

__device__ __forceinline__ float bf_lo(unsigned int u) { return __uint_as_float(u << 16); }
__device__ __forceinline__ float bf_hi(unsigned int u) { return __uint_as_float(u & 0xFFFF0000u); }
__device__ __forceinline__ unsigned int pk2(float a, float b) {
    __hip_bfloat162 p = __float22bfloat162_rn(make_float2(a, b));
    union { __hip_bfloat162 h; unsigned int u; } cv; cv.h = p; return cv.u;
}

// Workspace: bcnt[NBP] boff[NBP] gcur[NBP] ebuf[E] rowptr[NBUK*64+4] dinv[N]
//            y1a[N*8] y1b[N*8] pA[N] y2[N]

__global__ void k_zeroB(int* __restrict__ bcnt) {
    int i = blockIdx.x * blockDim.x + threadIdx.x;
    if (i < NBP) bcnt[i] = 0;
}

// global bucket histogram via per-block LDS histogram (int4 edge reads)
__launch_bounds__(256)
__global__ void k_bhist(const int* __restrict__ dst, int* __restrict__ bcnt) {
    __shared__ int h[NBP];
    for (int i = threadIdx.x; i < NBP; i += 256) h[i] = 0;
    __syncthreads();
    const int4* d4 = (const int4*)dst;
    int stride = gridDim.x * blockDim.x;
    for (int e = blockIdx.x * blockDim.x + threadIdx.x; e < N_EDGES / 4; e += stride) {
        int4 v = d4[e];
        atomicAdd(&h[v.x >> BSH], 1);
        atomicAdd(&h[v.y >> BSH], 1);
        atomicAdd(&h[v.z >> BSH], 1);
        atomicAdd(&h[v.w >> BSH], 1);
    }
    __syncthreads();
    for (int i = threadIdx.x; i < NBP; i += 256)
        if (h[i]) atomicAdd(&bcnt[i], h[i]);
}

// single block: exclusive scan of bcnt[NBP] -> boff, working copy -> gcur
__global__ void k_bscan(const int* __restrict__ bcnt, int* __restrict__ boff,
                        int* __restrict__ gcur) {
    __shared__ int s[256];
    int t = threadIdx.x;
    int c[8]; int sum = 0;
    #pragma unroll
    for (int k = 0; k < 8; ++k) { c[k] = bcnt[t * 8 + k]; sum += c[k]; }
    s[t] = sum; __syncthreads();
    for (int d = 1; d < 256; d <<= 1) {
        int add = (t >= d) ? s[t - d] : 0;
        __syncthreads();
        s[t] += add;
        __syncthreads();
    }
    int excl = s[t] - sum;
    #pragma unroll
    for (int k = 0; k < 8; ++k) {
        boff[t * 8 + k] = excl;
        gcur[t * 8 + k] = excl;
        excl += c[k];
    }
}

// Partition edges into bucket-ordered ebuf. SINGLE-PASS: edges held in registers,
// rank from the returning LDS atomicAdd of the count phase (no second global read,
// no second LDS-atomic round). 512 threads = 8 waves/block for latency hiding.
// packed edge = (dst & 63) << 20 | src   (src < 2^17)
__launch_bounds__(512)
__global__ void k_bfill(const int* __restrict__ src, const int* __restrict__ dst,
                        int* __restrict__ gcur, unsigned int* __restrict__ ebuf) {
    __shared__ int cntA[NBP];               // chunk-local counts
    __shared__ int offA[NBP];               // exclusive offsets within chunk
    __shared__ int baseG[NBP];              // reserved global base per bucket
    __shared__ int ssum[512];
    __shared__ unsigned int stage[FCHUNK];  // 32 KB
    __shared__ unsigned short sbuk[FCHUNK]; // 16 KB: bucket id per stage slot
    int t = threadIdx.x;
    int e0 = blockIdx.x * FCHUNK;
    int eN = min(e0 + FCHUNK, N_EDGES) - e0;       // multiple of 4
    int n4 = eN >> 2;
    const int4* d4 = (const int4*)(dst + e0);
    const int4* s4 = (const int4*)(src + e0);
    int4 dd[4], ss[4];
    #pragma unroll
    for (int k = 0; k < 4; ++k) {
        int i = t + k * 512;
        if (i < n4) { dd[k] = d4[i]; ss[k] = s4[i]; }   // issued up-front, independent
    }
    for (int i = t; i < NBP; i += 512) cntA[i] = 0;
    __syncthreads();
    // count + rank in one round (returning atomics)
    unsigned short rk[16];
    #pragma unroll
    for (int k = 0; k < 4; ++k) {
        int i = t + k * 512;
        if (i < n4) {
            rk[4 * k + 0] = (unsigned short)atomicAdd(&cntA[dd[k].x >> BSH], 1);
            rk[4 * k + 1] = (unsigned short)atomicAdd(&cntA[dd[k].y >> BSH], 1);
            rk[4 * k + 2] = (unsigned short)atomicAdd(&cntA[dd[k].z >> BSH], 1);
            rk[4 * k + 3] = (unsigned short)atomicAdd(&cntA[dd[k].w >> BSH], 1);
        }
    }
    __syncthreads();
    // LDS exclusive scan cntA -> offA (4 elems/thread, 512-thread scan)
    {
        int c[4]; int sum = 0;
        #pragma unroll
        for (int k = 0; k < 4; ++k) { c[k] = cntA[t * 4 + k]; sum += c[k]; }
        ssum[t] = sum; __syncthreads();
        for (int d = 1; d < 512; d <<= 1) {
            int add = (t >= d) ? ssum[t - d] : 0;
            __syncthreads();
            ssum[t] += add;
            __syncthreads();
        }
        int excl = ssum[t] - sum;
        #pragma unroll
        for (int k = 0; k < 4; ++k) { offA[t * 4 + k] = excl; excl += c[k]; }
    }
    __syncthreads();
    // reserve global space per bucket
    for (int b = t; b < NBP; b += 512)
        if (cntA[b] > 0) baseG[b] = atomicAdd(&gcur[b], cntA[b]);
    // place packed edges into LDS stage from registers
    #pragma unroll
    for (int k = 0; k < 4; ++k) {
        int i = t + k * 512;
        if (i < n4) {
            int b0 = dd[k].x >> BSH, b1 = dd[k].y >> BSH;
            int b2 = dd[k].z >> BSH, b3 = dd[k].w >> BSH;
            int p0 = offA[b0] + rk[4 * k + 0];
            int p1 = offA[b1] + rk[4 * k + 1];
            int p2 = offA[b2] + rk[4 * k + 2];
            int p3 = offA[b3] + rk[4 * k + 3];
            stage[p0] = ((unsigned int)(dd[k].x & (BNODES - 1)) << 20) | (unsigned int)ss[k].x;
            stage[p1] = ((unsigned int)(dd[k].y & (BNODES - 1)) << 20) | (unsigned int)ss[k].y;
            stage[p2] = ((unsigned int)(dd[k].z & (BNODES - 1)) << 20) | (unsigned int)ss[k].z;
            stage[p3] = ((unsigned int)(dd[k].w & (BNODES - 1)) << 20) | (unsigned int)ss[k].w;
            sbuk[p0] = (unsigned short)b0;
            sbuk[p1] = (unsigned short)b1;
            sbuk[p2] = (unsigned short)b2;
            sbuk[p3] = (unsigned short)b3;
        }
    }
    __syncthreads();
    // coalesced flush: consecutive i within a bucket run -> consecutive ebuf addrs
    for (int i = t; i < eN; i += 512) {
        int b = sbuk[i];
        ebuf[baseG[b] + (i - offA[b])] = stage[i];
    }
}

// Per-bucket LDS counting sort by dlocal -> ebuf globally dst-sorted (CSR order).
// Also emits rowptr[v] (global row starts) and dinv[v] = rsqrt(deg+1).
__launch_bounds__(256)
__global__ void k_sort(unsigned int* __restrict__ ebuf, const int* __restrict__ boff,
                       const int* __restrict__ bcnt, int* __restrict__ rowptr,
                       float* __restrict__ dinv) {
    __shared__ unsigned int slab[SLAB];    // 12 KB
    __shared__ unsigned int slab2[SLAB];   // 12 KB
    __shared__ int hist[BNODES];
    __shared__ int scanx[BNODES];
    __shared__ int cur[BNODES];
    int t = threadIdx.x;
    int b = blockIdx.x;
    int s0 = boff[b];
    int n = min(bcnt[b], SLAB);
    if (t < BNODES) hist[t] = 0;
    __syncthreads();
    for (int i = t; i < n; i += 256) {
        unsigned int w = ebuf[s0 + i];
        slab[i] = w;
        atomicAdd(&hist[w >> 20], 1);
    }
    __syncthreads();
    if (t == 0) {
        int r = 0;
        for (int l = 0; l < BNODES; ++l) { scanx[l] = r; r += hist[l]; }
    }
    __syncthreads();
    if (t < BNODES) {
        cur[t] = scanx[t];
        int v = b * BNODES + t;
        rowptr[v] = s0 + scanx[t];
        if (v < N_NODES) dinv[v] = rsqrtf((float)(hist[t] + 1));
    }
    if (b == 0 && t == 0) rowptr[NBUK * BNODES] = N_EDGES;
    __syncthreads();
    for (int i = t; i < n; i += 256) {
        unsigned int w = slab[i];
        int pos = atomicAdd(&cur[w >> 20], 1);
        slab2[pos] = w;
    }
    __syncthreads();
    for (int i = t; i < n; i += 256) ebuf[s0 + i] = slab2[i];
}

// y1 = bf16-packed rows of dinv[v] * (x @ W1), via MFMA 16x16x32 bf16.
// Column-split output: y1a = cols 0..15 (32B rows), y1b = cols 16..31.
__launch_bounds__(256)
__global__ void k_gemm1(const float* __restrict__ x, const float* __restrict__ W1,
                        const float* __restrict__ dinv, unsigned int* __restrict__ y1a,
                        unsigned int* __restrict__ y1b) {
    int wv = (blockIdx.x * 256 + threadIdx.x) >> 6;
    int nwaves = (gridDim.x * 256) >> 6;
    int lane = threadIdx.x & 63;
    int m = lane & 15;
    int kb = lane >> 4;                   // 0..3
    v8s Bf[2][4];                         // B fragments: [ntile][kstep]
    #pragma unroll
    for (int tt = 0; tt < 2; ++tt)
        #pragma unroll
        for (int s = 0; s < 4; ++s) {
            union { unsigned int u[4]; v8s v; } ub;
            #pragma unroll
            for (int jj = 0; jj < 4; ++jj) {
                int k = s * 32 + kb * 8 + jj * 2;
                ub.u[jj] = pk2(W1[k * HID + tt * 16 + m], W1[(k + 1) * HID + tt * 16 + m]);
            }
            Bf[tt][s] = ub.v;
        }
    for (int tile = wv; tile < N_NODES / 16; tile += nwaves) {   // 6250 exact, no tail
        int base = tile * 16;
        const float* xr = x + (size_t)(base + m) * DIM;
        v4f acc0 = {0.f, 0.f, 0.f, 0.f}, acc1 = {0.f, 0.f, 0.f, 0.f};
        #pragma unroll
        for (int s = 0; s < 4; ++s) {
            float4 xa = *(const float4*)(xr + s * 32 + kb * 8);
            float4 xb = *(const float4*)(xr + s * 32 + kb * 8 + 4);
            union { unsigned int u[4]; v8s v; } ua;
            ua.u[0] = pk2(xa.x, xa.y); ua.u[1] = pk2(xa.z, xa.w);
            ua.u[2] = pk2(xb.x, xb.y); ua.u[3] = pk2(xb.z, xb.w);
            acc0 = __builtin_amdgcn_mfma_f32_16x16x32_bf16(ua.v, Bf[0][s], acc0, 0, 0, 0);
            acc1 = __builtin_amdgcn_mfma_f32_16x16x32_bf16(ua.v, Bf[1][s], acc1, 0, 0, 0);
        }
        float4 dv = *(const float4*)(dinv + base + kb * 4);     // rows kb*4..kb*4+3
        float d[4] = {dv.x, dv.y, dv.z, dv.w};
        #pragma unroll
        for (int r = 0; r < 4; ++r) {
            float v0 = acc0[r] * d[r];
            float v1 = acc1[r] * d[r];
            float p0 = __shfl_xor(v0, 1, 64);                   // partner col
            float p1 = __shfl_xor(v1, 1, 64);
            if ((m & 1) == 0) {
                int node = base + kb * 4 + r;
                y1a[node * 8 + (m >> 1)] = pk2(v0, p0);         // cols m, m+1
                y1b[node * 8 + (m >> 1)] = pk2(v1, p1);         // cols 16+m, 17+m
            }
        }
    }
}

// Layer-1 gather over an L2-RESIDENT half-table (3.2MB): 32 lanes per node =
// 4 edge-subsets x 8 uint-lanes; batch of 32 edges per broadcast ebuf load,
// 8 independent 32B row loads in flight. HALF=0: cols 0..15 -> out_h, pA.
// HALF=1: cols 16..31 -> out_h, y2 = dinv*(pA + pB).
template <int HALF>
__launch_bounds__(256)
__global__ void k_gather1(const int* __restrict__ rowptr, const unsigned int* __restrict__ ebuf,
                          const unsigned int* __restrict__ yh, const float* __restrict__ dinv,
                          const float* __restrict__ b1, const float* __restrict__ W2,
                          float* __restrict__ out_h, float* __restrict__ pA,
                          float* __restrict__ y2) {
    int t = threadIdx.x;
    int node = blockIdx.x * 8 + (t >> 5);
    if (node >= N_NODES) return;
    int lane = t & 31;
    int sub = lane >> 3;                  // edge subset 0..3
    int c = lane & 7;                     // uint index in 32B row (cols 2c, 2c+1)
    int start = rowptr[node], end = rowptr[node + 1];
    float l0 = 0.f, l1 = 0.f, l2 = 0.f, l3 = 0.f;
    float h0 = 0.f, h1 = 0.f, h2 = 0.f, h3 = 0.f;
    int j = start;
    for (; j + 32 <= end; j += 32) {
        unsigned int w = ebuf[j + lane];             // 32 consecutive words
        unsigned int e0 = (unsigned int)__shfl((int)w, 0  + sub, 32) & 0xFFFFF;
        unsigned int e1 = (unsigned int)__shfl((int)w, 4  + sub, 32) & 0xFFFFF;
        unsigned int e2 = (unsigned int)__shfl((int)w, 8  + sub, 32) & 0xFFFFF;
        unsigned int e3 = (unsigned int)__shfl((int)w, 12 + sub, 32) & 0xFFFFF;
        unsigned int e4 = (unsigned int)__shfl((int)w, 16 + sub, 32) & 0xFFFFF;
        unsigned int e5 = (unsigned int)__shfl((int)w, 20 + sub, 32) & 0xFFFFF;
        unsigned int e6 = (unsigned int)__shfl((int)w, 24 + sub, 32) & 0xFFFFF;
        unsigned int e7 = (unsigned int)__shfl((int)w, 28 + sub, 32) & 0xFFFFF;
        unsigned int v0 = yh[(size_t)e0 * 8 + c];    // 8 independent 32B row loads
        unsigned int v1 = yh[(size_t)e1 * 8 + c];
        unsigned int v2 = yh[(size_t)e2 * 8 + c];
        unsigned int v3 = yh[(size_t)e3 * 8 + c];
        unsigned int v4 = yh[(size_t)e4 * 8 + c];
        unsigned int v5 = yh[(size_t)e5 * 8 + c];
        unsigned int v6 = yh[(size_t)e6 * 8 + c];
        unsigned int v7 = yh[(size_t)e7 * 8 + c];
        l0 += bf_lo(v0); h0 += bf_hi(v0);
        l1 += bf_lo(v1); h1 += bf_hi(v1);
        l2 += bf_lo(v2); h2 += bf_hi(v2);
        l3 += bf_lo(v3); h3 += bf_hi(v3);
        l0 += bf_lo(v4); h0 += bf_hi(v4);
        l1 += bf_lo(v5); h1 += bf_hi(v5);
        l2 += bf_lo(v6); h2 += bf_hi(v6);
        l3 += bf_lo(v7); h3 += bf_hi(v7);
    }
    int navail = end - j;                 // 0..31 tail edges
    if (navail > 0) {
        unsigned int w = ebuf[min(j + lane, end - 1)];
        #pragma unroll
        for (int k = 0; k < 8; ++k) {
            int idx = k * 4 + sub;
            unsigned int u = (unsigned int)__shfl((int)w, idx, 32) & 0xFFFFF;
            if (idx < navail) {
                unsigned int v = yh[(size_t)u * 8 + c];
                l0 += bf_lo(v); h0 += bf_hi(v);
            }
        }
    }
    float alo = (l0 + l1) + (l2 + l3);
    float ahi = (h0 + h1) + (h2 + h3);
    alo += __shfl_xor(alo, 8, 32);        // combine edge subsets
    ahi += __shfl_xor(ahi, 8, 32);
    alo += __shfl_xor(alo, 16, 32);
    ahi += __shfl_xor(ahi, 16, 32);
    unsigned int sv = yh[(size_t)node * 8 + c];      // self loop
    alo += bf_lo(sv); ahi += bf_hi(sv);
    float di = dinv[node];
    int col = HALF * 16 + 2 * c;
    float hlo = fmaxf(fmaf(di, alo, b1[col]), 0.f);
    float hhi = fmaxf(fmaf(di, ahi, b1[col + 1]), 0.f);
    float p = hlo * W2[col] + hhi * W2[col + 1];
    p += __shfl_xor(p, 1, 32);
    p += __shfl_xor(p, 2, 32);
    p += __shfl_xor(p, 4, 32);            // sum over 8 col-lanes (subsets identical)
    if (sub == 0) {
        *(float2*)&out_h[(size_t)node * HID + col] = make_float2(hlo, hhi);
        if (c == 0) {
            if (HALF == 0) pA[node] = p;
            else           y2[node] = di * (pA[node] + p);
        }
    }
}

// Layer-2 gather, CSR-style: 32 lanes stride the node's edge run (coalesced ebuf reads).
__launch_bounds__(256)
__global__ void k_gather2(const int* __restrict__ rowptr, const unsigned int* __restrict__ ebuf,
                          const float* __restrict__ y2, const float* __restrict__ dinv,
                          const float* __restrict__ b2, float* __restrict__ scores) {
    int t = threadIdx.x;
    int node = blockIdx.x * 8 + (t >> 5);
    int lane = t & 31;
    if (node >= N_NODES) return;
    int start = rowptr[node], end = rowptr[node + 1];
    float acc = 0.f;
    for (int j = start + lane; j < end; j += 32)
        acc += y2[ebuf[j] & 0xFFFFF];
    #pragma unroll
    for (int off = 16; off > 0; off >>= 1) acc += __shfl_xor(acc, off);
    if (lane == 0) scores[node] = dinv[node] * (acc + y2[node]) + b2[0];
}

extern "C" void kernel_launch(void* const* d_in, const int* in_sizes, int n_in,
                              void* d_out, int out_size, void* d_ws, size_t ws_size,
                              hipStream_t stream) {
    const float* x  = (const float*)d_in[0];
    const int* ei   = (const int*)d_in[1];
    const float* W1 = (const float*)d_in[2];
    const float* b1 = (const float*)d_in[3];
    const float* W2 = (const float*)d_in[4];
    const float* b2 = (const float*)d_in[5];

    const int* src = ei;             // edge_index[0]
    const int* dst = ei + N_EDGES;   // edge_index[1]

    int* bcnt = (int*)d_ws;                             // NBP
    int* boff = bcnt + NBP;                             // NBP
    int* gcur = boff + NBP;                             // NBP
    unsigned int* ebuf = (unsigned int*)(gcur + NBP);   // E
    int* rowptr = (int*)(ebuf + N_EDGES);               // NBUK*BNODES + 4
    float* dinv = (float*)(rowptr + NBUK * BNODES + 4); // N
    unsigned int* y1a = (unsigned int*)(dinv + N_NODES);// N*8 (bf16 cols 0..15)
    unsigned int* y1b = y1a + (size_t)N_NODES * 8;      // N*8 (bf16 cols 16..31)
    float* pA   = (float*)(y1b + (size_t)N_NODES * 8);  // N
    float* y2   = pA + N_NODES;                         // N

    float* out_h = (float*)d_out;                       // N*HID
    float* out_s = out_h + (size_t)N_NODES * HID;       // N

    k_zeroB <<<NBP / 256, 256, 0, stream>>>(bcnt);
    k_bhist <<<512, 256, 0, stream>>>(dst, bcnt);
    k_bscan <<<1, 256, 0, stream>>>(bcnt, boff, gcur);
    k_bfill <<<NFILL, 512, 0, stream>>>(src, dst, gcur, ebuf);
    k_sort  <<<NBUK, 256, 0, stream>>>(ebuf, boff, bcnt, rowptr, dinv);
    k_gemm1 <<<512, 256, 0, stream>>>(x, W1, dinv, y1a, y1b);
    k_gather1<0><<<(N_NODES + 7) / 8, 256, 0, stream>>>(rowptr, ebuf, y1a, dinv, b1, W2, out_h, pA, y2);
    k_gather1<1><<<(N_NODES + 7) / 8, 256, 0, stream>>>(rowptr, ebuf, y1b, dinv, b1, W2, out_h, pA, y2);
    k_gather2<<<(N_NODES + 7) / 8, 256, 0, stream>>>(rowptr, ebuf, y2, dinv, b2, out_s);
}

// Round 12
// 137.091 us; speedup vs baseline: 1.3628x; 1.1975x over previous
//
#include <hip/hip_runtime.h>
#include <hip/hip_bf16.h>

#define N_NODES 100000
#define N_EDGES 3200000
#define DIM 128
#define HID 32

#define BSH 6                                   // bucket = dst >> 6
#define BNODES (1 << BSH)                       // 64 nodes per bucket
#define NBUK ((N_NODES + BNODES - 1) >> BSH)    // 1563
#define NBP 2048                                // padded (pow2) bucket count
#define FCHUNK 8192                             // edges per partition block
#define NFILL ((N_EDGES + FCHUNK - 1) / FCHUNK) // 391
#define CAP 3072                                // fixed slab per bucket (mean 2048, +22 sigma)

typedef short v8s __attribute__((ext_vector_type(8)));
typedef float v4f __attribute__((ext_vector_type(4)));

__device__ __forceinline__ float bf_lo(unsigned int u) { return __uint_as_float(u << 16); }
__device__ __forceinline__ float bf_hi(unsigned int u) { return __uint_as_float(u & 0xFFFF0000u); }
__device__ __forceinline__ unsigned int pk2(float a, float b) {
    __hip_bfloat162 p = __float22bfloat162_rn(make_float2(a, b));
    union { __hip_bfloat162 h; unsigned int u; } cv; cv.h = p; return cv.u;
}

// Workspace: bcnt[NBP] ebuf[NBUK*CAP] rowbeg[N] rowend[N] dinv[N] y1a[N*8] y1b[N*8] pA[N] y2[N]

__global__ void k_zeroB(int* __restrict__ bcnt) {
    int i = blockIdx.x * blockDim.x + threadIdx.x;
    if (i < NBP) bcnt[i] = 0;
}

// Partition edges into per-bucket slabs (ebuf[b*CAP ...]). SINGLE-PASS: edges held in
// registers, rank from the returning LDS atomicAdd; global base = b*CAP + bcnt bump.
// packed edge = (dst & 63) << 20 | src   (src < 2^17)
__launch_bounds__(512)
__global__ void k_bfill(const int* __restrict__ src, const int* __restrict__ dst,
                        int* __restrict__ bcnt, unsigned int* __restrict__ ebuf) {
    __shared__ int cntA[NBP];               // chunk-local counts
    __shared__ int offA[NBP];               // exclusive offsets within chunk
    __shared__ int baseG[NBP];              // reserved global base per bucket
    __shared__ int ssum[512];
    __shared__ unsigned int stage[FCHUNK];  // 32 KB
    __shared__ unsigned short sbuk[FCHUNK]; // 16 KB: bucket id per stage slot
    int t = threadIdx.x;
    int e0 = blockIdx.x * FCHUNK;
    int eN = min(e0 + FCHUNK, N_EDGES) - e0;       // multiple of 4
    int n4 = eN >> 2;
    const int4* d4 = (const int4*)(dst + e0);
    const int4* s4 = (const int4*)(src + e0);
    int4 dd[4], ss[4];
    #pragma unroll
    for (int k = 0; k < 4; ++k) {
        int i = t + k * 512;
        if (i < n4) { dd[k] = d4[i]; ss[k] = s4[i]; }   // issued up-front, independent
    }
    for (int i = t; i < NBP; i += 512) cntA[i] = 0;
    __syncthreads();
    // count + rank in one round (returning atomics)
    unsigned short rk[16];
    #pragma unroll
    for (int k = 0; k < 4; ++k) {
        int i = t + k * 512;
        if (i < n4) {
            rk[4 * k + 0] = (unsigned short)atomicAdd(&cntA[dd[k].x >> BSH], 1);
            rk[4 * k + 1] = (unsigned short)atomicAdd(&cntA[dd[k].y >> BSH], 1);
            rk[4 * k + 2] = (unsigned short)atomicAdd(&cntA[dd[k].z >> BSH], 1);
            rk[4 * k + 3] = (unsigned short)atomicAdd(&cntA[dd[k].w >> BSH], 1);
        }
    }
    __syncthreads();
    // LDS exclusive scan cntA -> offA (4 elems/thread)
    {
        int c[4]; int sum = 0;
        #pragma unroll
        for (int k = 0; k < 4; ++k) { c[k] = cntA[t * 4 + k]; sum += c[k]; }
        ssum[t] = sum; __syncthreads();
        for (int d = 1; d < 512; d <<= 1) {
            int add = (t >= d) ? ssum[t - d] : 0;
            __syncthreads();
            ssum[t] += add;
            __syncthreads();
        }
        int excl = ssum[t] - sum;
        #pragma unroll
        for (int k = 0; k < 4; ++k) { offA[t * 4 + k] = excl; excl += c[k]; }
    }
    __syncthreads();
    // reserve global slab space per bucket
    for (int b = t; b < NBP; b += 512)
        if (cntA[b] > 0) baseG[b] = b * CAP + atomicAdd(&bcnt[b], cntA[b]);
    // place packed edges into LDS stage from registers
    #pragma unroll
    for (int k = 0; k < 4; ++k) {
        int i = t + k * 512;
        if (i < n4) {
            int b0 = dd[k].x >> BSH, b1 = dd[k].y >> BSH;
            int b2 = dd[k].z >> BSH, b3 = dd[k].w >> BSH;
            int p0 = offA[b0] + rk[4 * k + 0];
            int p1 = offA[b1] + rk[4 * k + 1];
            int p2 = offA[b2] + rk[4 * k + 2];
            int p3 = offA[b3] + rk[4 * k + 3];
            stage[p0] = ((unsigned int)(dd[k].x & (BNODES - 1)) << 20) | (unsigned int)ss[k].x;
            stage[p1] = ((unsigned int)(dd[k].y & (BNODES - 1)) << 20) | (unsigned int)ss[k].y;
            stage[p2] = ((unsigned int)(dd[k].z & (BNODES - 1)) << 20) | (unsigned int)ss[k].z;
            stage[p3] = ((unsigned int)(dd[k].w & (BNODES - 1)) << 20) | (unsigned int)ss[k].w;
            sbuk[p0] = (unsigned short)b0;
            sbuk[p1] = (unsigned short)b1;
            sbuk[p2] = (unsigned short)b2;
            sbuk[p3] = (unsigned short)b3;
        }
    }
    __syncthreads();
    // coalesced flush: consecutive i within a bucket run -> consecutive ebuf addrs
    for (int i = t; i < eN; i += 512) {
        int b = sbuk[i];
        ebuf[baseG[b] + (i - offA[b])] = stage[i];
    }
}

// Per-bucket LDS counting sort by dlocal -> slab dst-sorted (CSR runs).
// Emits rowbeg/rowend (slab coords) and dinv[v] = rsqrt(deg+1).
__launch_bounds__(256)
__global__ void k_sort(unsigned int* __restrict__ ebuf, const int* __restrict__ bcnt,
                       int* __restrict__ rowbeg, int* __restrict__ rowend,
                       float* __restrict__ dinv) {
    __shared__ unsigned int slab[CAP];     // 12 KB
    __shared__ unsigned int slab2[CAP];    // 12 KB
    __shared__ int hist[BNODES];
    __shared__ int scanx[BNODES];
    __shared__ int cur[BNODES];
    int t = threadIdx.x;
    int b = blockIdx.x;
    int s0 = b * CAP;
    int n = min(bcnt[b], CAP);
    if (t < BNODES) hist[t] = 0;
    __syncthreads();
    for (int i = t; i < n; i += 256) {
        unsigned int w = ebuf[s0 + i];
        slab[i] = w;
        atomicAdd(&hist[w >> 20], 1);
    }
    __syncthreads();
    if (t == 0) {
        int r = 0;
        for (int l = 0; l < BNODES; ++l) { scanx[l] = r; r += hist[l]; }
    }
    __syncthreads();
    if (t < BNODES) {
        cur[t] = scanx[t];
        int v = b * BNODES + t;
        if (v < N_NODES) {
            rowbeg[v] = s0 + scanx[t];
            rowend[v] = s0 + scanx[t] + hist[t];
            dinv[v] = rsqrtf((float)(hist[t] + 1));
        }
    }
    __syncthreads();
    for (int i = t; i < n; i += 256) {
        unsigned int w = slab[i];
        int pos = atomicAdd(&cur[w >> 20], 1);
        slab2[pos] = w;
    }
    __syncthreads();
    for (int i = t; i < n; i += 256) ebuf[s0 + i] = slab2[i];
}

// y1 = bf16-packed rows of dinv[v] * (x @ W1), via MFMA 16x16x32 bf16.
// Column-split output: y1a = cols 0..15 (32B rows), y1b = cols 16..31.
__launch_bounds__(256)
__global__ void k_gemm1(const float* __restrict__ x, const float* __restrict__ W1,
                        const float* __restrict__ dinv, unsigned int* __restrict__ y1a,
                        unsigned int* __restrict__ y1b) {
    int wv = (blockIdx.x * 256 + threadIdx.x) >> 6;
    int nwaves = (gridDim.x * 256) >> 6;
    int lane = threadIdx.x & 63;
    int m = lane & 15;
    int kb = lane >> 4;                   // 0..3
    v8s Bf[2][4];                         // B fragments: [ntile][kstep]
    #pragma unroll
    for (int tt = 0; tt < 2; ++tt)
        #pragma unroll
        for (int s = 0; s < 4; ++s) {
            union { unsigned int u[4]; v8s v; } ub;
            #pragma unroll
            for (int jj = 0; jj < 4; ++jj) {
                int k = s * 32 + kb * 8 + jj * 2;
                ub.u[jj] = pk2(W1[k * HID + tt * 16 + m], W1[(k + 1) * HID + tt * 16 + m]);
            }
            Bf[tt][s] = ub.v;
        }
    for (int tile = wv; tile < N_NODES / 16; tile += nwaves) {   // 6250 exact, no tail
        int base = tile * 16;
        const float* xr = x + (size_t)(base + m) * DIM;
        v4f acc0 = {0.f, 0.f, 0.f, 0.f}, acc1 = {0.f, 0.f, 0.f, 0.f};
        #pragma unroll
        for (int s = 0; s < 4; ++s) {
            float4 xa = *(const float4*)(xr + s * 32 + kb * 8);
            float4 xb = *(const float4*)(xr + s * 32 + kb * 8 + 4);
            union { unsigned int u[4]; v8s v; } ua;
            ua.u[0] = pk2(xa.x, xa.y); ua.u[1] = pk2(xa.z, xa.w);
            ua.u[2] = pk2(xb.x, xb.y); ua.u[3] = pk2(xb.z, xb.w);
            acc0 = __builtin_amdgcn_mfma_f32_16x16x32_bf16(ua.v, Bf[0][s], acc0, 0, 0, 0);
            acc1 = __builtin_amdgcn_mfma_f32_16x16x32_bf16(ua.v, Bf[1][s], acc1, 0, 0, 0);
        }
        float4 dv = *(const float4*)(dinv + base + kb * 4);     // rows kb*4..kb*4+3
        float d[4] = {dv.x, dv.y, dv.z, dv.w};
        #pragma unroll
        for (int r = 0; r < 4; ++r) {
            float v0 = acc0[r] * d[r];
            float v1 = acc1[r] * d[r];
            float p0 = __shfl_xor(v0, 1, 64);                   // partner col
            float p1 = __shfl_xor(v1, 1, 64);
            if ((m & 1) == 0) {
                int node = base + kb * 4 + r;
                y1a[node * 8 + (m >> 1)] = pk2(v0, p0);         // cols m, m+1
                y1b[node * 8 + (m >> 1)] = pk2(v1, p1);         // cols 16+m, 17+m
            }
        }
    }
}

// Layer-1 gather over an L2-RESIDENT half-table (3.2MB). 32 lanes per node =
// 8 edge-subsets x 4 uint2-lanes; batch of 32 edges per broadcast ebuf load,
// 4 independent uint2 (8B) row loads in flight = 8 edges per load instruction.
// HALF=0: cols 0..15 -> out_h, pA.  HALF=1: cols 16..31 -> out_h, y2.
template <int HALF>
__launch_bounds__(256)
__global__ void k_gather1(const int* __restrict__ rowbeg, const int* __restrict__ rowend,
                          const unsigned int* __restrict__ ebuf,
                          const unsigned int* __restrict__ yh, const float* __restrict__ dinv,
                          const float* __restrict__ b1, const float* __restrict__ W2,
                          float* __restrict__ out_h, float* __restrict__ pA,
                          float* __restrict__ y2) {
    int t = threadIdx.x;
    int node = blockIdx.x * 8 + (t >> 5);
    if (node >= N_NODES) return;
    int lane = t & 31;
    int sub = lane >> 2;                  // edge subset 0..7
    int c2 = lane & 3;                    // uint2 index in 32B row (cols 4c2..4c2+3)
    int start = rowbeg[node], end = rowend[node];
    float a0[4] = {0.f, 0.f, 0.f, 0.f};
    float a1[4] = {0.f, 0.f, 0.f, 0.f};
    float a2[4] = {0.f, 0.f, 0.f, 0.f};
    float a3[4] = {0.f, 0.f, 0.f, 0.f};
    const uint2* y2b = (const uint2*)yh;
    int j = start;
    for (; j + 32 <= end; j += 32) {
        unsigned int w = ebuf[j + lane];             // 32 consecutive words
        unsigned int e0 = (unsigned int)__shfl((int)w, 0  + sub, 32) & 0xFFFFF;
        unsigned int e1 = (unsigned int)__shfl((int)w, 8  + sub, 32) & 0xFFFFF;
        unsigned int e2 = (unsigned int)__shfl((int)w, 16 + sub, 32) & 0xFFFFF;
        unsigned int e3 = (unsigned int)__shfl((int)w, 24 + sub, 32) & 0xFFFFF;
        uint2 v0 = y2b[e0 * 4 + c2];                 // 4 independent 8B row loads
        uint2 v1 = y2b[e1 * 4 + c2];
        uint2 v2 = y2b[e2 * 4 + c2];
        uint2 v3 = y2b[e3 * 4 + c2];
        a0[0] += bf_lo(v0.x); a0[1] += bf_hi(v0.x); a0[2] += bf_lo(v0.y); a0[3] += bf_hi(v0.y);
        a1[0] += bf_lo(v1.x); a1[1] += bf_hi(v1.x); a1[2] += bf_lo(v1.y); a1[3] += bf_hi(v1.y);
        a2[0] += bf_lo(v2.x); a2[1] += bf_hi(v2.x); a2[2] += bf_lo(v2.y); a2[3] += bf_hi(v2.y);
        a3[0] += bf_lo(v3.x); a3[1] += bf_hi(v3.x); a3[2] += bf_lo(v3.y); a3[3] += bf_hi(v3.y);
    }
    int navail = end - j;                 // 0..31 tail edges
    if (navail > 0) {
        unsigned int w = ebuf[min(j + lane, end - 1)];
        #pragma unroll
        for (int k = 0; k < 4; ++k) {
            int idx = k * 8 + sub;
            unsigned int u = (unsigned int)__shfl((int)w, idx, 32) & 0xFFFFF;
            if (idx < navail) {
                uint2 v = y2b[u * 4 + c2];
                a0[0] += bf_lo(v.x); a0[1] += bf_hi(v.x);
                a0[2] += bf_lo(v.y); a0[3] += bf_hi(v.y);
            }
        }
    }
    float q[4];
    #pragma unroll
    for (int i = 0; i < 4; ++i) q[i] = (a0[i] + a1[i]) + (a2[i] + a3[i]);
    #pragma unroll
    for (int i = 0; i < 4; ++i) {
        q[i] += __shfl_xor(q[i], 4, 32);  // combine 8 edge subsets
        q[i] += __shfl_xor(q[i], 8, 32);
        q[i] += __shfl_xor(q[i], 16, 32);
    }
    uint2 sv = y2b[(unsigned int)node * 4 + c2];     // self loop
    q[0] += bf_lo(sv.x); q[1] += bf_hi(sv.x); q[2] += bf_lo(sv.y); q[3] += bf_hi(sv.y);
    float di = dinv[node];
    int col = HALF * 16 + 4 * c2;
    float h[4], p = 0.f;
    #pragma unroll
    for (int i = 0; i < 4; ++i) {
        h[i] = fmaxf(fmaf(di, q[i], b1[col + i]), 0.f);
        p = fmaf(h[i], W2[col + i], p);
    }
    p += __shfl_xor(p, 1, 32);            // reduce over the 4 c2 lanes
    p += __shfl_xor(p, 2, 32);
    if (sub == 0) {
        *(float4*)&out_h[(size_t)node * HID + col] = make_float4(h[0], h[1], h[2], h[3]);
        if (c2 == 0) {
            if (HALF == 0) pA[node] = p;
            else           y2[node] = di * (pA[node] + p);
        }
    }
}

// Layer-2 gather: 32 lanes stride the node's slab run (coalesced ebuf reads).
__launch_bounds__(256)
__global__ void k_gather2(const int* __restrict__ rowbeg, const int* __restrict__ rowend,
                          const unsigned int* __restrict__ ebuf, const float* __restrict__ y2,
                          const float* __restrict__ dinv, const float* __restrict__ b2,
                          float* __restrict__ scores) {
    int t = threadIdx.x;
    int node = blockIdx.x * 8 + (t >> 5);
    int lane = t & 31;
    if (node >= N_NODES) return;
    int start = rowbeg[node], end = rowend[node];
    float acc = 0.f;
    for (int j = start + lane; j < end; j += 32)
        acc += y2[ebuf[j] & 0xFFFFF];
    #pragma unroll
    for (int off = 16; off > 0; off >>= 1) acc += __shfl_xor(acc, off);
    if (lane == 0) scores[node] = dinv[node] * (acc + y2[node]) + b2[0];
}

extern "C" void kernel_launch(void* const* d_in, const int* in_sizes, int n_in,
                              void* d_out, int out_size, void* d_ws, size_t ws_size,
                              hipStream_t stream) {
    const float* x  = (const float*)d_in[0];
    const int* ei   = (const int*)d_in[1];
    const float* W1 = (const float*)d_in[2];
    const float* b1 = (const float*)d_in[3];
    const float* W2 = (const float*)d_in[4];
    const float* b2 = (const float*)d_in[5];

    const int* src = ei;             // edge_index[0]
    const int* dst = ei + N_EDGES;   // edge_index[1]

    int* bcnt = (int*)d_ws;                              // NBP
    unsigned int* ebuf = (unsigned int*)(bcnt + NBP);    // NBUK*CAP (slabbed)
    int* rowbeg = (int*)(ebuf + (size_t)NBUK * CAP);     // N
    int* rowend = rowbeg + N_NODES;                      // N
    float* dinv = (float*)(rowend + N_NODES);            // N
    unsigned int* y1a = (unsigned int*)(dinv + N_NODES); // N*8 (bf16 cols 0..15)
    unsigned int* y1b = y1a + (size_t)N_NODES * 8;       // N*8 (bf16 cols 16..31)
    float* pA   = (float*)(y1b + (size_t)N_NODES * 8);   // N
    float* y2   = pA + N_NODES;                          // N

    float* out_h = (float*)d_out;                        // N*HID
    float* out_s = out_h + (size_t)N_NODES * HID;        // N

    k_zeroB <<<NBP / 256, 256, 0, stream>>>(bcnt);
    k_bfill <<<NFILL, 512, 0, stream>>>(src, dst, bcnt, ebuf);
    k_sort  <<<NBUK, 256, 0, stream>>>(ebuf, bcnt, rowbeg, rowend, dinv);
    k_gemm1 <<<512, 256, 0, stream>>>(x, W1, dinv, y1a, y1b);
    k_gather1<0><<<(N_NODES + 7) / 8, 256, 0, stream>>>(rowbeg, rowend, ebuf, y1a, dinv, b1, W2, out_h, pA, y2);
    k_gather1<1><<<(N_NODES + 7) / 8, 256, 0, stream>>>(rowbeg, rowend, ebuf, y1b, dinv, b1, W2, out_h, pA, y2);
    k_gather2<<<(N_NODES + 7) / 8, 256, 0, stream>>>(rowbeg, rowend, ebuf, y2, dinv, b2, out_s);
}